// Round 12
// baseline (17.810 us; speedup 1.0000x reference)
//
#include <hip/hip_runtime.h>
#include <hip/hip_bf16.h>

#define B_N   32768
#define G_N   2500
#define NB    20
#define GS    50
#define WR    12                   // row window: >=6 cells = 3.9 sigma each side
#define WC    16                   // col window: >=8 cells = 5.2 sigma each side

static __device__ __forceinline__ float fast_exp2(float a) {
#if __has_builtin(__builtin_amdgcn_exp2f)
    return __builtin_amdgcn_exp2f(a);
#else
    return exp2f(a);
#endif
}

// C2 = -2 * log2(e): w = exp(-sq/(2*0.5^2)) = exp(-2*sq) = 2^(C2*sq)
#define C2f     (-2.8853900817779268f)
#define STEP    (16.0f / 49.0f)    // linspace(-8,8,50) spacing
#define INVSTEP (49.0f / 16.0f)

// ---- single kernel: 4 samples per wave; 16 lanes (columns) per sample --------
// R11 post-mortem: latency-chain-bound (251 cyc/wave vs ~140 cyc VALU work;
// instruction cuts moved nothing). This layout: lane=(smp,c); each lane walks
// its column's 12 rows unrolled -> 24 independent loads in flight per wave
// (was 6), butterfly reduce 6 rounds -> 4 (within 16-lane groups), and the 4
// outputs per wave land in one contiguous 32B store.
__global__ __launch_bounds__(256) void main_kernel(
    const float* __restrict__ t, const float* __restrict__ x,
    const float* __restrict__ te, const float* __restrict__ adj,
    const int* __restrict__ counts, float* __restrict__ out)
{
    int lane = threadIdx.x & 63;
    int smp  = lane >> 4;          // sample-within-wave 0..3
    int c    = lane & 15;          // column-within-window 0..15
    int wid  = blockIdx.x * 16 + ((threadIdx.x >> 6) << 2) + smp;  // sample id

    // ---- exact O(1) bucketize: candidate +-1, corrected vs real edges -------
    float tv = t[wid];
    int tb = (int)(tv * 20.0f);
    tb = (tb > NB - 1) ? (NB - 1) : tb;
    float e_lo = te[tb];               // safe: tb in [0,19]
    float e_hi = te[tb + 1];           // safe: index <= 20 (te has 21 entries)
    if (tb > 0 && e_lo >= tv)            tb--;   // true tb = #{te_k < tv}
    else if (tb < NB - 1 && e_hi < tv)   tb++;

    float2 xv = *reinterpret_cast<const float2*>(&x[2 * wid]);
    float x0 = xv.x, x1 = xv.y;

    // ---- floor-centered 12x16 window, clamped to grid -----------------------
    int i0 = (int)floorf((x0 + 8.0f) * INVSTEP) - (WR / 2 - 1);  // [fl-5, fl+6]
    i0 = (i0 < 0) ? 0 : ((i0 > GS - WR) ? (GS - WR) : i0);
    int j0 = (int)floorf((x1 + 8.0f) * INVSTEP) - (WC / 2 - 1);  // [fl-7, fl+8]
    j0 = (j0 < 0) ? 0 : ((j0 > GS - WC) ? (GS - WC) : j0);

    float dj  = x1 - (-8.0f + STEP * (float)(j0 + c));
    float dj2 = dj * dj;

    int cell0 = tb * G_N + i0 * GS + (j0 + c);
    const float2* __restrict__ pa = reinterpret_cast<const float2*>(adj) + cell0;
    const int*    __restrict__ pc = counts + cell0;

    // ---- walk all 12 rows of this column (unrolled: 24 loads in flight) -----
    float w = 0.0f, a0 = 0.0f, a1 = 0.0f;
    #pragma unroll
    for (int r = 0; r < WR; ++r) {
        float di = x0 - (-8.0f + STEP * (float)(i0 + r));
        float uv = fast_exp2(C2f * fmaf(di, di, dj2));   // exp(-2(di^2+dj^2))
        int    m = pc[r * GS];
        float2 q = pa[r * GS];
        uv = (m > 0) ? uv : 0.0f;                        // populated-cell mask
        w  += uv;
        a0  = fmaf(uv, q.x, a0);
        a1  = fmaf(uv, q.y, a1);
    }

    // ---- butterfly reduce within each 16-lane group (4 rounds) --------------
    #pragma unroll
    for (int off = 8; off; off >>= 1) {
        w  += __shfl_xor(w,  off, 64);
        a0 += __shfl_xor(a0, off, 64);
        a1 += __shfl_xor(a1, off, 64);
    }

    if (c == 0) {
        float inv = -1.0f / (w + 1e-10f);
        // 4 samples/wave -> 4 contiguous float2 = one 32B-coalesced store
        *reinterpret_cast<float2*>(&out[2 * wid]) = make_float2(a0 * inv, a1 * inv);
    }
}

extern "C" void kernel_launch(void* const* d_in, const int* in_sizes, int n_in,
                              void* d_out, int out_size, void* d_ws, size_t ws_size,
                              hipStream_t stream)
{
    const float* t      = (const float*)d_in[0];   // (B,1)
    const float* x      = (const float*)d_in[1];   // (B,2)
    const float* adj    = (const float*)d_in[3];   // (NB,G,2)
    const float* te     = (const float*)d_in[4];   // (NB+1,)
    const int*   counts = (const int*)d_in[5];     // (NB,G)
    float*       out    = (float*)d_out;

    main_kernel<<<B_N / 16, 256, 0, stream>>>(t, x, te, adj, counts, out);
}

// Round 13
// 11.584 us; speedup vs baseline: 1.5374x; 1.5374x over previous
//
#include <hip/hip_runtime.h>
#include <hip/hip_bf16.h>

#define B_N   32768
#define G_N   2500
#define NB    20
#define GS    50
#define WR    12                   // row window: >=6 cells = 3.9 sigma each side
#define WC    16                   // col window: >=8 cells = 5.2 sigma each side

static __device__ __forceinline__ float fast_exp2(float a) {
#if __has_builtin(__builtin_amdgcn_exp2f)
    return __builtin_amdgcn_exp2f(a);
#else
    return exp2f(a);
#endif
}

// C2 = -2 * log2(e): w = exp(-sq/(2*0.5^2)) = exp(-2*sq) = 2^(C2*sq)
#define C2f     (-2.8853900817779268f)
#define STEP    (16.0f / 49.0f)    // linspace(-8,8,50) spacing
#define INVSTEP (49.0f / 16.0f)

// AMD canonical wave64 DPP reduction step: v += dpp_move(v); after
// row_shr:1,2,4,8 each row's lane15 holds the row sum; row_bcast:15 then
// row_bcast:31 cascade row sums upward; lane 63 holds the full 64-lane sum.
// bound_ctrl=true -> out-of-range lanes contribute 0. Pure VALU (no LDS pipe),
// replacing 18 serial ds_bpermute (~30cyc ea) with 18 ~4-8cyc DPP adds.
#define DPPADD(v, ctrl)                                                        \
    ((v) + __int_as_float(__builtin_amdgcn_update_dpp(                         \
               0, __float_as_int(v), (ctrl), 0xf, 0xf, true)))

// ---- single kernel: one wave per sample; lane=(rr,c) tiles a 12x16 window ----
// R12 post-mortem: 4 samples/wave (more ILP, 4x fewer waves) regressed 33% ->
// TLP wins; keep R11's layout. This round cuts the two serial chains: DPP
// reduce (tail) and scalar-pipe s_loads for the wave-uniform head (t/x/te).
__global__ __launch_bounds__(256) void main_kernel(
    const float* __restrict__ t, const float* __restrict__ x,
    const float* __restrict__ te, const float* __restrict__ adj,
    const int* __restrict__ counts, float* __restrict__ out)
{
    int lane = threadIdx.x & 63;
    int rr   = lane >> 4;          // row-within-chunk 0..3
    int c    = lane & 15;          // col-within-window 0..15
    // wave-uniform sample id in an SGPR -> t/x loads become s_load (K$ pipe)
    int wid  = __builtin_amdgcn_readfirstlane(blockIdx.x * 4 + (threadIdx.x >> 6));

    // ---- exact O(1) bucketize: candidate +-1, corrected vs real edges -------
    float tv = t[wid];
    int tb = (int)(tv * 20.0f);
    tb = (tb > NB - 1) ? (NB - 1) : tb;
    tb = __builtin_amdgcn_readfirstlane(tb);     // uniform -> te s_loads
    float e_lo = te[tb];               // safe: tb in [0,19]
    float e_hi = te[tb + 1];           // safe: index <= 20 (te has 21 entries)
    if (tb > 0 && e_lo >= tv)            tb--;   // true tb = #{te_k < tv}
    else if (tb < NB - 1 && e_hi < tv)   tb++;

    float2 xv = *reinterpret_cast<const float2*>(&x[2 * wid]);
    float x0 = xv.x, x1 = xv.y;

    // ---- floor-centered 12x16 window, clamped to grid -----------------------
    int i0 = (int)floorf((x0 + 8.0f) * INVSTEP) - (WR / 2 - 1);  // [fl-5, fl+6]
    i0 = (i0 < 0) ? 0 : ((i0 > GS - WR) ? (GS - WR) : i0);
    int j0 = (int)floorf((x1 + 8.0f) * INVSTEP) - (WC / 2 - 1);  // [fl-7, fl+8]
    j0 = (j0 < 0) ? 0 : ((j0 > GS - WC) ? (GS - WC) : j0);

    float dj  = x1 - (-8.0f + STEP * (float)(j0 + c));
    float dj2 = dj * dj;

    int cell0 = tb * G_N + (i0 + rr) * GS + (j0 + c);
    const float2* __restrict__ pa = reinterpret_cast<const float2*>(adj) + cell0;
    const int*    __restrict__ pc = counts + cell0;

    // ---- accumulate 3 row-chunks per lane; one exp2 per element -------------
    float w = 0.0f, a0 = 0.0f, a1 = 0.0f;
    #pragma unroll
    for (int k = 0; k < WR / 4; ++k) {
        float di = x0 - (-8.0f + STEP * (float)(i0 + 4 * k + rr));
        float uv = fast_exp2(C2f * fmaf(di, di, dj2));   // exp(-2(di^2+dj^2))
        int    m = pc[4 * k * GS];
        float2 q = pa[4 * k * GS];
        uv = (m > 0) ? uv : 0.0f;                        // populated-cell mask
        w  += uv;
        a0  = fmaf(uv, q.x, a0);
        a1  = fmaf(uv, q.y, a1);
    }

    // ---- DPP wave64 reduction (pure VALU); lane 63 holds each total ---------
    w  = DPPADD(w,  0x111); w  = DPPADD(w,  0x112);
    w  = DPPADD(w,  0x114); w  = DPPADD(w,  0x118);
    w  = DPPADD(w,  0x142); w  = DPPADD(w,  0x143);
    a0 = DPPADD(a0, 0x111); a0 = DPPADD(a0, 0x112);
    a0 = DPPADD(a0, 0x114); a0 = DPPADD(a0, 0x118);
    a0 = DPPADD(a0, 0x142); a0 = DPPADD(a0, 0x143);
    a1 = DPPADD(a1, 0x111); a1 = DPPADD(a1, 0x112);
    a1 = DPPADD(a1, 0x114); a1 = DPPADD(a1, 0x118);
    a1 = DPPADD(a1, 0x142); a1 = DPPADD(a1, 0x143);

    if (lane == 63) {
        float inv = -1.0f / (w + 1e-10f);
        *reinterpret_cast<float2*>(&out[2 * wid]) = make_float2(a0 * inv, a1 * inv);
    }
}

extern "C" void kernel_launch(void* const* d_in, const int* in_sizes, int n_in,
                              void* d_out, int out_size, void* d_ws, size_t ws_size,
                              hipStream_t stream)
{
    const float* t      = (const float*)d_in[0];   // (B,1)
    const float* x      = (const float*)d_in[1];   // (B,2)
    const float* adj    = (const float*)d_in[3];   // (NB,G,2)
    const float* te     = (const float*)d_in[4];   // (NB+1,)
    const int*   counts = (const int*)d_in[5];     // (NB,G)
    float*       out    = (float*)d_out;

    main_kernel<<<B_N / 4, 256, 0, stream>>>(t, x, te, adj, counts, out);
}